// Round 10
// baseline (843.493 us; speedup 1.0000x reference)
//
#include <hip/hip_runtime.h>

#define N_NODES 50000
#define NE      500000
#define HIDD    128
#define TDIM    32

__device__ __forceinline__ float leaky(float z) { return z >= 0.f ? z : 0.2f * z; }

// ---------------------------------------------------------------------------
// R10 GEMM core: 128 rows/block, 8x8 tile/thread, K chunked by 32, both
// operands in LDS. Two fixes over R9 (which was LDS-pipe-bound at 41% VALU,
// 4.8M bank conflicts):
//  * W stored even/odd-quad split: row [q0 q1 q2...] -> [evens | odds].
//    The wa read's 16 lane-addresses then sit at 16B stride (banks 4q,
//    2-way + 4-lane broadcast = free) instead of 32B stride (4-way).
//    wa = wl[k][c0>>1], wb = wl[k][64 + (c0>>1)].
//  * T14 register-prefetch staging: chunk k+1's global loads issue before
//    chunk k's FMA phase; LDS writes land after the barrier. HBM/L2 latency
//    hides under ~4096 cyc of FMA. +32 VGPR (spill tripwire: WRITE_SIZE).
// X swizzle unchanged: row r quad c4 at phys (c4 ^ ((r>>3)&7)); read quad
// (kq ^ (g&7)) -> 4 g-groups hit distinct quads, 16-lane broadcast groups.
// Plain __launch_bounds__(256): R7 lesson (min-waves arg clamps VGPR->spill).
// ---------------------------------------------------------------------------
__device__ __forceinline__ void load_x32(float4 px[4],
                                         const float* __restrict__ x,
                                         int nb, int kc, int t, int bound)
{
    #pragma unroll
    for (int i = 0; i < 4; ++i) {
        int idx = t + i * 256;              // 0..1023 quads
        int row = idx >> 3, c4 = idx & 7;
        px[i] = make_float4(0.f, 0.f, 0.f, 0.f);
        if (nb + row < bound)
            px[i] = *(const float4*)&x[(long)(nb + row) * HIDD + kc * 32 + c4 * 4];
    }
}

__device__ __forceinline__ void load_w32(float4 pw[4],
                                         const float* __restrict__ W,
                                         int kc, int t)
{
    #pragma unroll
    for (int i = 0; i < 4; ++i) {
        int idx = t + i * 256;              // 0..1023 quads
        int row = idx >> 5, c4 = idx & 31;
        pw[i] = *(const float4*)&W[(long)(kc * 32 + row) * HIDD + c4 * 4];
    }
}

__device__ __forceinline__ void write_x32(float (*xs)[32], const float4 px[4], int t)
{
    #pragma unroll
    for (int i = 0; i < 4; ++i) {
        int idx = t + i * 256;
        int row = idx >> 3, c4 = idx & 7;
        int col = (c4 ^ ((row >> 3) & 7)) << 2;
        *(float4*)&xs[row][col] = px[i];
    }
}

__device__ __forceinline__ void write_w32(float (*wl)[HIDD], const float4 pw[4], int t)
{
    #pragma unroll
    for (int i = 0; i < 4; ++i) {
        int idx = t + i * 256;
        int row = idx >> 5, c4 = idx & 31;
        int p = ((c4 & 1) << 4) | (c4 >> 1);   // even/odd quad split
        *(float4*)&wl[row][p * 4] = pw[i];
    }
}

__device__ __forceinline__ void gemm_chunk(const float (*xs)[32],
                                           const float (*wl)[HIDD],
                                           int g, int c0, float acc[8][8])
{
    const int wq = c0 >> 1;                 // phys float offset of even quad
    #pragma unroll 1
    for (int kq = 0; kq < 8; ++kq) {
        float4 xv[8];
        const int col = ((kq ^ (g & 7)) << 2);
        #pragma unroll
        for (int nn = 0; nn < 8; ++nn)
            xv[nn] = *(const float4*)&xs[g * 8 + nn][col];
        #pragma unroll
        for (int kk = 0; kk < 4; ++kk) {
            const float4 wa = *(const float4*)&wl[kq * 4 + kk][wq];
            const float4 wb = *(const float4*)&wl[kq * 4 + kk][64 + wq];
            const float wv[8] = {wa.x, wa.y, wa.z, wa.w, wb.x, wb.y, wb.z, wb.w};
            #pragma unroll
            for (int nn = 0; nn < 8; ++nn) {
                const float xk = (kk == 0) ? xv[nn].x : (kk == 1) ? xv[nn].y
                               : (kk == 2) ? xv[nn].z : xv[nn].w;
                #pragma unroll
                for (int j = 0; j < 8; ++j) acc[nn][j] += xk * wv[j];
            }
        }
    }
}

// Per-head attention reduction: p = sum_c leaky(proj[c])*att[h][c&31],
// reduced over the 4 threads (q&3) sharing head h. Writer: q%4==0.
__device__ __forceinline__ void att_reduce_store(
    float acc[8][8], const float* __restrict__ att, int off,
    int nb, int g, int q, int h, float* __restrict__ outp)
{
    const float* ap = att + h * 96 + off + 8 * (q & 3);
    const float4 A0 = *(const float4*)ap, A1 = *(const float4*)(ap + 4);
    const float av[8] = {A0.x, A0.y, A0.z, A0.w, A1.x, A1.y, A1.z, A1.w};
    #pragma unroll
    for (int nn = 0; nn < 8; ++nn) {
        float p = 0.f;
        #pragma unroll
        for (int j = 0; j < 8; ++j) p += leaky(acc[nn][j]) * av[j];
        p += __shfl_down(p, 2, 4);
        p += __shfl_down(p, 1, 4);
        const int node = nb + g * 8 + nn;
        if ((q & 3) == 0 && node < N_NODES) outp[node * 4 + h] = p;
    }
}

// ---------------------------------------------------------------------------
// Kernel A: per-node projections (sj, si, V).
// Grid = 3 x projBlocks — each block does ONE of {Ws->sj, Wv->V, Wd->si}.
// ---------------------------------------------------------------------------
__global__ __launch_bounds__(256) void node_proj_kernel(
    const float* __restrict__ xsrc, const float* __restrict__ xdst,
    const float* __restrict__ Ws, const float* __restrict__ Wd,
    const float* __restrict__ Wv, const float* __restrict__ att,
    float* __restrict__ sj, float* __restrict__ si, float* __restrict__ V,
    int nblk)
{
    __shared__ float xs[128][32];         // 16 KB
    __shared__ float wl[32][HIDD];        // 16 KB
    const int m = blockIdx.x % 3;         // 0:Ws->sj 1:Wv->V 2:Wd->si
    const int b = blockIdx.x / 3;
    const int t = threadIdx.x;
    const int g = t >> 4, q = t & 15;
    const int c0 = q * 8, h = q >> 2;
    const int nb = b * 128;

    const float* x = (m == 2) ? xdst : xsrc;
    const float* W = (m == 0) ? Ws : (m == 1) ? Wv : Wd;

    float acc[8][8];
    #pragma unroll
    for (int a = 0; a < 8; ++a)
        #pragma unroll
        for (int bb = 0; bb < 8; ++bb) acc[a][bb] = 0.f;

    float4 px[4], pw[4];
    load_x32(px, x, nb, 0, t, N_NODES);
    load_w32(pw, W, 0, t);

    #pragma unroll 1
    for (int kc = 0; kc < 4; ++kc) {
        write_x32(xs, px, t);
        write_w32(wl, pw, t);
        __syncthreads();
        if (kc < 3) {                     // prefetch next chunk under the FMAs
            load_x32(px, x, nb, kc + 1, t, N_NODES);
            load_w32(pw, W, kc + 1, t);
        }
        gemm_chunk(xs, wl, g, c0, acc);
        __syncthreads();
    }

    if (m == 1) {
        #pragma unroll
        for (int nn = 0; nn < 8; ++nn) {
            const int node = nb + g * 8 + nn;
            if (node < N_NODES) {
                *(float4*)&V[(long)node * HIDD + c0] =
                    make_float4(acc[nn][0], acc[nn][1], acc[nn][2], acc[nn][3]);
                *(float4*)&V[(long)node * HIDD + c0 + 4] =
                    make_float4(acc[nn][4], acc[nn][5], acc[nn][6], acc[nn][7]);
            }
        }
    } else if (m == 0) {
        att_reduce_store(acc, att, 0, nb, g, q, h, sj);
    } else {
        att_reduce_store(acc, att, 32, nb, g, q, h, si);
    }
}

// ---------------------------------------------------------------------------
// CSR build (R6): both directions in one pass each.
// ---------------------------------------------------------------------------
__global__ __launch_bounds__(256) void count2_kernel(
    const int* __restrict__ ed0, const int* __restrict__ ed1,
    int* __restrict__ cnt)
{
    const int EB = (NE + 255) / 256;
    const int b = blockIdx.x;
    const int dir = b >= EB;
    const int e = (b - dir * EB) * 256 + threadIdx.x;
    const int* ed = dir ? ed1 : ed0;
    if (e < NE) atomicAdd(&cnt[dir * N_NODES + ed[e]], 1);
}

#define SCAN_T 1024
#define SCAN_CHUNK 49
__global__ __launch_bounds__(1024) void scan2_kernel(
    const int* __restrict__ cnt, int* __restrict__ rowptr)
{
    __shared__ int part[SCAN_T];
    const int dir = blockIdx.x;
    const int* c = cnt + dir * N_NODES;
    int* rp = rowptr + dir * (N_NODES + 8);
    const int t = threadIdx.x;
    const int b = t * SCAN_CHUNK;
    const int e = min(b + SCAN_CHUNK, N_NODES);
    int s = 0;
    for (int i = b; i < e; ++i) s += c[i];
    part[t] = s;
    __syncthreads();
    for (int off = 1; off < SCAN_T; off <<= 1) {
        int v = (t >= off) ? part[t - off] : 0;
        __syncthreads();
        part[t] += v;
        __syncthreads();
    }
    int run = (t > 0) ? part[t - 1] : 0;
    for (int i = b; i < e; ++i) { rp[i] = run; run += c[i]; }
    if (t == SCAN_T - 1) rp[N_NODES] = part[SCAN_T - 1];
}

__global__ __launch_bounds__(256) void scatter2_kernel(
    const int* __restrict__ ed0, const int* __restrict__ ed1,
    const int* __restrict__ rowptr, int* __restrict__ cursor,
    int* __restrict__ eord)
{
    const int EB = (NE + 255) / 256;
    const int b = blockIdx.x;
    const int dir = b >= EB;
    const int e = (b - dir * EB) * 256 + threadIdx.x;
    if (e < NE) {
        const int* ed = dir ? ed1 : ed0;
        const int d = ed[e];
        const int pos = rowptr[dir * (N_NODES + 8) + d]
                      + atomicAdd(&cursor[dir * N_NODES + d], 1);
        eord[dir * NE + pos] = e;
    }
}

// ---------------------------------------------------------------------------
// Kernel B: per-edge logits + exp (no atomics).
// Wt (16 KB) staged once into LDS with the even/odd-quad swizzle.
// Register-tiled GEMM: 128 edges/block, 8 edges x 8 cols per thread, K=32.
// ---------------------------------------------------------------------------
__global__ __launch_bounds__(256, 4) void edge_logits_kernel(
    const int* __restrict__ ei, const float* __restrict__ tfeat,
    const float* __restrict__ Wt, const float* __restrict__ att,
    const float* __restrict__ sj, const float* __restrict__ si,
    float* __restrict__ exbuf)
{
    __shared__ float ts[128][TDIM];       // 16 KB
    __shared__ float wt[TDIM][HIDD];      // 16 KB
    const int t = threadIdx.x;
    const int g = t >> 4, q = t & 15;
    const int c0 = q * 8, h = q >> 2;
    const int wq = c0 >> 1;
    const int eb = blockIdx.x * 128;

    #pragma unroll
    for (int i = 0; i < 4; ++i) {
        int idx = t + i * 256;
        int row = idx >> 3, c4 = idx & 7;
        int col = (c4 ^ ((row >> 3) & 7)) << 2;
        float4 v = make_float4(0.f, 0.f, 0.f, 0.f);
        if (eb + row < NE)
            v = *(const float4*)&tfeat[(long)(eb + row) * TDIM + c4 * 4];
        *(float4*)&ts[row][col] = v;
    }
    {
        float4 pw[4];
        load_w32(pw, Wt, 0, t);
        write_w32(wt, pw, t);
    }
    __syncthreads();

    float acc[8][8];
    #pragma unroll
    for (int a = 0; a < 8; ++a)
        #pragma unroll
        for (int b = 0; b < 8; ++b) acc[a][b] = 0.f;

    #pragma unroll 1
    for (int k4 = 0; k4 < 8; ++k4) {
        float4 xv[8];
        const int col = ((k4 ^ (g & 7)) << 2);
        #pragma unroll
        for (int nn = 0; nn < 8; ++nn)
            xv[nn] = *(const float4*)&ts[g * 8 + nn][col];
        #pragma unroll
        for (int kk = 0; kk < 4; ++kk) {
            const float4 wa = *(const float4*)&wt[k4 * 4 + kk][wq];
            const float4 wb = *(const float4*)&wt[k4 * 4 + kk][64 + wq];
            const float wv[8] = {wa.x, wa.y, wa.z, wa.w, wb.x, wb.y, wb.z, wb.w};
            #pragma unroll
            for (int nn = 0; nn < 8; ++nn) {
                const float xk = (kk == 0) ? xv[nn].x : (kk == 1) ? xv[nn].y
                               : (kk == 2) ? xv[nn].z : xv[nn].w;
                #pragma unroll
                for (int j = 0; j < 8; ++j) acc[nn][j] += xk * wv[j];
            }
        }
    }

    const float* ap = att + h * 96 + 64 + 8 * (q & 3);
    const float4 A0 = *(const float4*)ap, A1 = *(const float4*)(ap + 4);
    const float av[8] = {A0.x, A0.y, A0.z, A0.w, A1.x, A1.y, A1.z, A1.w};
    float st[8];
    #pragma unroll
    for (int nn = 0; nn < 8; ++nn) {
        float p = 0.f;
        #pragma unroll
        for (int j = 0; j < 8; ++j) p += leaky(acc[nn][j]) * av[j];
        p += __shfl_down(p, 2, 4);
        p += __shfl_down(p, 1, 4);
        st[nn] = p;
    }
    if ((q & 3) == 0) {
        #pragma unroll
        for (int nn = 0; nn < 8; ++nn) {
            const int e = eb + g * 8 + nn;
            if (e < NE) {
                const int src = ei[e], dst = ei[NE + e];
                exbuf[e * 4 + h] =
                    __expf(sj[src * 4 + h] + si[dst * 4 + h] + st[nn]);
            }
        }
    }
}

// ---------------------------------------------------------------------------
// Kernel C: CSR gather — one wave per dst, single pass.
// Edge ids loaded VECTORIZED per 64-chunk, broadcast via v_readlane;
// 4 edges per iteration so 12 independent global loads are in flight.
// ---------------------------------------------------------------------------
__global__ __launch_bounds__(256) void gather_kernel(
    const int* __restrict__ rowptr, const int* __restrict__ eord,
    const int* __restrict__ eisrc, const float* __restrict__ tfeat,
    const float* __restrict__ exbuf, const float* __restrict__ Wt,
    const float* __restrict__ V, float* __restrict__ agg)
{
    __shared__ float WtS[TDIM * HIDD];   // 16 KB, natural [k][d]
    __shared__ float uS[4][HIDD];
    const int t = threadIdx.x;
    #pragma unroll
    for (int i = 0; i < 4; ++i)
        *(float4*)&WtS[(t + i * 256) * 4] = *(const float4*)&Wt[(t + i * 256) * 4];
    __syncthreads();

    const int w = t >> 6, l = t & 63;
    const int dst = blockIdx.x * 4 + w;              // exact: 12500*4 = 50000
    const int h = l >> 4, d0 = 2 * l, k0 = d0 & 31;
    const int beg = rowptr[dst], end = rowptr[dst + 1];

    float s = 0.f, a0 = 0.f, a1 = 0.f, u0 = 0.f, u1 = 0.f;

    for (int cb = beg; cb < end; cb += 64) {
        const int m = min(64, end - cb);
        int e_v = 0, s_v = 0;
        if (l < m) {
            e_v = eord[cb + l];                       // coalesced
            s_v = eisrc[e_v];                         // gather, but vector
        }
        int i = 0;
        #pragma unroll 1
        for (; i + 4 <= m; i += 4) {
            const int ea = __builtin_amdgcn_readlane(e_v, i);
            const int eb2 = __builtin_amdgcn_readlane(e_v, i + 1);
            const int ec = __builtin_amdgcn_readlane(e_v, i + 2);
            const int ed = __builtin_amdgcn_readlane(e_v, i + 3);
            const int sa = __builtin_amdgcn_readlane(s_v, i);
            const int sb = __builtin_amdgcn_readlane(s_v, i + 1);
            const int sc = __builtin_amdgcn_readlane(s_v, i + 2);
            const int sd = __builtin_amdgcn_readlane(s_v, i + 3);
            const float  xa = exbuf[ea * 4 + h];
            const float  xb = exbuf[eb2 * 4 + h];
            const float  xc = exbuf[ec * 4 + h];
            const float  xd = exbuf[ed * 4 + h];
            const float2 va = *(const float2*)&V[(long)sa * HIDD + d0];
            const float2 vb = *(const float2*)&V[(long)sb * HIDD + d0];
            const float2 vc = *(const float2*)&V[(long)sc * HIDD + d0];
            const float2 vd = *(const float2*)&V[(long)sd * HIDD + d0];
            const float2 ta = *(const float2*)&tfeat[(long)ea * TDIM + k0];
            const float2 tb = *(const float2*)&tfeat[(long)eb2 * TDIM + k0];
            const float2 tc = *(const float2*)&tfeat[(long)ec * TDIM + k0];
            const float2 td = *(const float2*)&tfeat[(long)ed * TDIM + k0];
            s  += xa;            s  += xb;            s  += xc;            s  += xd;
            a0 += xa * va.x;     a0 += xb * vb.x;     a0 += xc * vc.x;     a0 += xd * vd.x;
            a1 += xa * va.y;     a1 += xb * vb.y;     a1 += xc * vc.y;     a1 += xd * vd.y;
            u0 += xa * ta.x;     u0 += xb * tb.x;     u0 += xc * tc.x;     u0 += xd * td.x;
            u1 += xa * ta.y;     u1 += xb * tb.y;     u1 += xc * tc.y;     u1 += xd * td.y;
        }
        #pragma unroll 1
        for (; i < m; ++i) {
            const int e   = __builtin_amdgcn_readlane(e_v, i);
            const int src = __builtin_amdgcn_readlane(s_v, i);
            const float  ex = exbuf[e * 4 + h];
            const float2 vv = *(const float2*)&V[(long)src * HIDD + d0];
            const float2 tk = *(const float2*)&tfeat[(long)e * TDIM + k0];
            s  += ex;
            a0 += ex * vv.x;  a1 += ex * vv.y;
            u0 += ex * tk.x;  u1 += ex * tk.y;
        }
    }
    *(float2*)&uS[w][d0] = make_float2(u0, u1);      // (h, k0) lives at idx d0
    __syncthreads();

    const float inv = 1.f / (s + 1e-16f);
    float t0 = 0.f, t1 = 0.f;
    #pragma unroll
    for (int k = 0; k < TDIM; ++k) {
        const float uu = uS[w][h * 32 + k];
        const float2 wv = *(const float2*)&WtS[k * HIDD + d0];
        t0 += uu * wv.x;
        t1 += uu * wv.y;
    }
    *(float2*)&agg[(long)dst * HIDD + d0] =
        make_float2((a0 + t0) * inv, (a1 + t1) * inv);
}

// ---------------------------------------------------------------------------
// Kernel D (fused user+item): out = LN(h + agg@Wout + bout)*lnw + lnb
// R10: prefetch-pipelined dual-operand staging + W swizzle, as node_proj.
// LN via shfl over the 16 threads of each node group.
// ---------------------------------------------------------------------------
__global__ __launch_bounds__(256) void out_kernel(
    const float* __restrict__ agg_u, const float* __restrict__ agg_i,
    const float* __restrict__ h_u,   const float* __restrict__ h_i,
    const float* __restrict__ Wo_u,  const float* __restrict__ Wo_i,
    const float* __restrict__ bo_u,  const float* __restrict__ bo_i,
    const float* __restrict__ lw_u,  const float* __restrict__ lw_i,
    const float* __restrict__ lb_u,  const float* __restrict__ lb_i,
    float* __restrict__ out, int nblk)
{
    __shared__ float ag[128][32];        // 16 KB
    __shared__ float wl[32][HIDD];       // 16 KB
    const int dir = blockIdx.x >= nblk;
    const int b   = blockIdx.x - dir * nblk;
    const float* agg  = dir ? agg_i : agg_u;
    const float* hx   = dir ? h_i   : h_u;
    const float* Wout = dir ? Wo_i  : Wo_u;
    const float* bout = dir ? bo_i  : bo_u;
    const float* lnw  = dir ? lw_i  : lw_u;
    const float* lnb  = dir ? lb_i  : lb_u;
    float* outp = out + (long)dir * N_NODES * HIDD;

    const int t = threadIdx.x;
    const int g = t >> 4, q = t & 15;
    const int c0 = q * 8;
    const int l = t & 63;
    const int nb = b * 128;

    float acc[8][8];
    #pragma unroll
    for (int a = 0; a < 8; ++a)
        #pragma unroll
        for (int bb = 0; bb < 8; ++bb) acc[a][bb] = 0.f;

    float4 px[4], pw[4];
    load_x32(px, agg, nb, 0, t, N_NODES);
    load_w32(pw, Wout, 0, t);

    #pragma unroll 1
    for (int kc = 0; kc < 4; ++kc) {
        write_x32(ag, px, t);
        write_w32(wl, pw, t);
        __syncthreads();
        if (kc < 3) {
            load_x32(px, agg, nb, kc + 1, t, N_NODES);
            load_w32(pw, Wout, kc + 1, t);
        }
        gemm_chunk(ag, wl, g, c0, acc);
        __syncthreads();
    }

    const float4 B0 = *(const float4*)&bout[c0], B1 = *(const float4*)&bout[c0+4];
    const float4 G0 = *(const float4*)&lnw[c0],  G1 = *(const float4*)&lnw[c0+4];
    const float4 L0 = *(const float4*)&lnb[c0],  L1 = *(const float4*)&lnb[c0+4];
    const float bo[8] = {B0.x,B0.y,B0.z,B0.w,B1.x,B1.y,B1.z,B1.w};
    const float gw[8] = {G0.x,G0.y,G0.z,G0.w,G1.x,G1.y,G1.z,G1.w};
    const float gb[8] = {L0.x,L0.y,L0.z,L0.w,L1.x,L1.y,L1.z,L1.w};

    #pragma unroll
    for (int nn = 0; nn < 8; ++nn) {
        const int node = nb + g * 8 + nn;
        const bool valid = node < N_NODES;
        float y[8];
        float4 H0 = make_float4(0,0,0,0), H1 = make_float4(0,0,0,0);
        if (valid) {
            H0 = *(const float4*)&hx[(long)node * HIDD + c0];
            H1 = *(const float4*)&hx[(long)node * HIDD + c0 + 4];
        }
        const float hv[8] = {H0.x,H0.y,H0.z,H0.w,H1.x,H1.y,H1.z,H1.w};
        float s1 = 0.f, s2 = 0.f;
        #pragma unroll
        for (int j = 0; j < 8; ++j) {
            y[j] = hv[j] + acc[nn][j] + bo[j];
            s1 += y[j];
            s2 += y[j] * y[j];
        }
        s1 += __shfl_down(s1, 8, 16); s2 += __shfl_down(s2, 8, 16);
        s1 += __shfl_down(s1, 4, 16); s2 += __shfl_down(s2, 4, 16);
        s1 += __shfl_down(s1, 2, 16); s2 += __shfl_down(s2, 2, 16);
        s1 += __shfl_down(s1, 1, 16); s2 += __shfl_down(s2, 1, 16);
        s1 = __shfl(s1, l & ~15);
        s2 = __shfl(s2, l & ~15);
        const float mu  = s1 * (1.f / 128.f);
        const float var = s2 * (1.f / 128.f) - mu * mu;
        const float inv = rsqrtf(var + 1e-5f);
        if (valid) {
            float o[8];
            #pragma unroll
            for (int j = 0; j < 8; ++j) o[j] = (y[j] - mu) * inv * gw[j] + gb[j];
            *(float4*)&outp[(long)node * HIDD + c0]     = make_float4(o[0],o[1],o[2],o[3]);
            *(float4*)&outp[(long)node * HIDD + c0 + 4] = make_float4(o[4],o[5],o[6],o[7]);
        }
    }
}

// ---------------------------------------------------------------------------
extern "C" void kernel_launch(void* const* d_in, const int* in_sizes, int n_in,
                              void* d_out, int out_size, void* d_ws, size_t ws_size,
                              hipStream_t stream)
{
    const float* h_user    = (const float*)d_in[0];
    const float* h_item    = (const float*)d_in[1];
    const int*   ei_ui     = (const int*)d_in[2];
    const float* t_ui      = (const float*)d_in[3];
    const int*   ei_iu     = (const int*)d_in[4];
    const float* t_iu      = (const float*)d_in[5];
    const float* W_src_ui  = (const float*)d_in[6];
    const float* W_dst_ui  = (const float*)d_in[7];
    const float* W_temp_ui = (const float*)d_in[8];
    const float* W_val_ui  = (const float*)d_in[9];
    const float* att_ui    = (const float*)d_in[10];
    const float* W_src_iu  = (const float*)d_in[11];
    const float* W_dst_iu  = (const float*)d_in[12];
    const float* W_temp_iu = (const float*)d_in[13];
    const float* W_val_iu  = (const float*)d_in[14];
    const float* att_iu    = (const float*)d_in[15];
    const float* Wout_user = (const float*)d_in[16];
    const float* bout_user = (const float*)d_in[17];
    const float* Wout_item = (const float*)d_in[18];
    const float* bout_item = (const float*)d_in[19];
    const float* lnw_user  = (const float*)d_in[20];
    const float* lnb_user  = (const float*)d_in[21];
    const float* lnw_item  = (const float*)d_in[22];
    const float* lnb_item  = (const float*)d_in[23];

    // workspace layout (R6: dual CSR — rowptr/cnt/eord doubled)
    float* agg_item = (float*)d_ws;
    float* agg_user = agg_item + (long)N_NODES * HIDD;
    float* V        = agg_user + (long)N_NODES * HIDD;
    float* sj       = V + (long)N_NODES * HIDD;
    float* si       = sj + (long)N_NODES * 4;
    float* exbuf    = si + (long)N_NODES * 4;
    int*   rowptr   = (int*)(exbuf + (long)NE * 4);   // [2][N_NODES+8]
    int*   cnt      = rowptr + 2 * (N_NODES + 8);     // [2][N_NODES]
    int*   eord     = cnt + 2 * N_NODES;              // [2][NE]

    const int edgeBlocks  = (NE + 255) / 256;         // 1954
    const int logitBlocks = (NE + 127) / 128;         // 3907
    const int dstBlocks   = N_NODES / 4;              // 12500
    const int projBlocks  = (N_NODES + 127) / 128;    // 391

    // --- CSR build for BOTH directions in one pass each ---
    hipMemsetAsync(cnt, 0, 2 * N_NODES * sizeof(int), stream);
    count2_kernel<<<2 * edgeBlocks, 256, 0, stream>>>(ei_ui + NE, ei_iu + NE, cnt);
    scan2_kernel<<<2, SCAN_T, 0, stream>>>(cnt, rowptr);
    hipMemsetAsync(cnt, 0, 2 * N_NODES * sizeof(int), stream);
    scatter2_kernel<<<2 * edgeBlocks, 256, 0, stream>>>(
        ei_ui + NE, ei_iu + NE, rowptr, cnt, eord);

    for (int dir = 0; dir < 2; ++dir) {
        const int*   ei   = dir == 0 ? ei_ui : ei_iu;
        const float* tf   = dir == 0 ? t_ui : t_iu;
        const float* xsrc = dir == 0 ? h_user : h_item;
        const float* xdst = dir == 0 ? h_item : h_user;
        const float* Ws   = dir == 0 ? W_src_ui : W_src_iu;
        const float* Wd   = dir == 0 ? W_dst_ui : W_dst_iu;
        const float* Wt   = dir == 0 ? W_temp_ui : W_temp_iu;
        const float* Wv   = dir == 0 ? W_val_ui : W_val_iu;
        const float* att  = dir == 0 ? att_ui : att_iu;
        float*       agg  = dir == 0 ? agg_item : agg_user;

        node_proj_kernel<<<3 * projBlocks, 256, 0, stream>>>(
            xsrc, xdst, Ws, Wd, Wv, att, sj, si, V, projBlocks);
        edge_logits_kernel<<<logitBlocks, 256, 0, stream>>>(
            ei, tf, Wt, att, sj, si, exbuf);
        gather_kernel<<<dstBlocks, 256, 0, stream>>>(
            rowptr + dir * (N_NODES + 8), eord + dir * NE,
            ei, tf, exbuf, Wt, V, agg);
    }

    out_kernel<<<2 * projBlocks, 256, 0, stream>>>(
        agg_user, agg_item, h_user, h_item,
        Wout_user, Wout_item, bout_user, bout_item,
        lnw_user, lnw_item, lnb_user, lnb_item,
        (float*)d_out, projBlocks);
}

// Round 11
// 802.090 us; speedup vs baseline: 1.0516x; 1.0516x over previous
//
#include <hip/hip_runtime.h>

#define N_NODES 50000
#define NE      500000
#define HIDD    128
#define TDIM    32

__device__ __forceinline__ float leaky(float z) { return z >= 0.f ? z : 0.2f * z; }

// ---------------------------------------------------------------------------
// R11 GEMM core: 128 rows/block, 8x8 tile/thread, K chunked by 32, both
// operands in LDS. R10 lessons applied:
//  * KEEP the W even/odd-quad split (conflicts 4.8M -> 0.6M): row
//    [q0 q1 q2...] stored as [evens | odds]; wa = wl[k][c0>>1],
//    wb = wl[k][64 + (c0>>1)] — 16B-stride lane addresses (2-way + 4-lane
//    broadcast = free) instead of 32B stride (4-way conflict).
//  * REVERT the register prefetch: it spilled to scratch (WRITE_SIZE
//    26.5 -> 76 MB, R10 tripwire). This inner loop's live set sits at the
//    allocator boundary; stage->sync->compute (R9 structure) is spill-free.
// X swizzle: row r quad c4 at phys (c4 ^ ((r>>3)&7)); read quad
// (kq ^ (g&7)) -> the 4 g-groups of a wave hit distinct quads.
// Plain __launch_bounds__(256): R7 lesson (min-waves arg clamps VGPR->spill).
// ---------------------------------------------------------------------------
__device__ __forceinline__ void stage_x32(float (*xs)[32],
                                          const float* __restrict__ x,
                                          int nb, int kc, int t, int bound)
{
    #pragma unroll
    for (int i = 0; i < 4; ++i) {
        int idx = t + i * 256;              // 0..1023 quads
        int row = idx >> 3, c4 = idx & 7;
        int col = (c4 ^ ((row >> 3) & 7)) << 2;
        float4 v = make_float4(0.f, 0.f, 0.f, 0.f);
        if (nb + row < bound)
            v = *(const float4*)&x[(long)(nb + row) * HIDD + kc * 32 + c4 * 4];
        *(float4*)&xs[row][col] = v;
    }
}

__device__ __forceinline__ void stage_w32(float (*wl)[HIDD],
                                          const float* __restrict__ W,
                                          int kc, int t)
{
    #pragma unroll
    for (int i = 0; i < 4; ++i) {
        int idx = t + i * 256;              // 0..1023 quads
        int row = idx >> 5, c4 = idx & 31;
        int p = ((c4 & 1) << 4) | (c4 >> 1);   // even/odd quad split
        *(float4*)&wl[row][p * 4] =
            *(const float4*)&W[(long)(kc * 32 + row) * HIDD + c4 * 4];
    }
}

__device__ __forceinline__ void gemm_chunk(const float (*xs)[32],
                                           const float (*wl)[HIDD],
                                           int g, int c0, float acc[8][8])
{
    const int wq = c0 >> 1;                 // phys float offset of even quad
    #pragma unroll 1
    for (int kq = 0; kq < 8; ++kq) {
        float4 xv[8];
        const int col = ((kq ^ (g & 7)) << 2);
        #pragma unroll
        for (int nn = 0; nn < 8; ++nn)
            xv[nn] = *(const float4*)&xs[g * 8 + nn][col];
        #pragma unroll
        for (int kk = 0; kk < 4; ++kk) {
            const float4 wa = *(const float4*)&wl[kq * 4 + kk][wq];
            const float4 wb = *(const float4*)&wl[kq * 4 + kk][64 + wq];
            const float wv[8] = {wa.x, wa.y, wa.z, wa.w, wb.x, wb.y, wb.z, wb.w};
            #pragma unroll
            for (int nn = 0; nn < 8; ++nn) {
                const float xk = (kk == 0) ? xv[nn].x : (kk == 1) ? xv[nn].y
                               : (kk == 2) ? xv[nn].z : xv[nn].w;
                #pragma unroll
                for (int j = 0; j < 8; ++j) acc[nn][j] += xk * wv[j];
            }
        }
    }
}

// Per-head attention reduction: p = sum_c leaky(proj[c])*att[h][c&31],
// reduced over the 4 threads (q&3) sharing head h. Writer: q%4==0.
__device__ __forceinline__ void att_reduce_store(
    float acc[8][8], const float* __restrict__ att, int off,
    int nb, int g, int q, int h, float* __restrict__ outp)
{
    const float* ap = att + h * 96 + off + 8 * (q & 3);
    const float4 A0 = *(const float4*)ap, A1 = *(const float4*)(ap + 4);
    const float av[8] = {A0.x, A0.y, A0.z, A0.w, A1.x, A1.y, A1.z, A1.w};
    #pragma unroll
    for (int nn = 0; nn < 8; ++nn) {
        float p = 0.f;
        #pragma unroll
        for (int j = 0; j < 8; ++j) p += leaky(acc[nn][j]) * av[j];
        p += __shfl_down(p, 2, 4);
        p += __shfl_down(p, 1, 4);
        const int node = nb + g * 8 + nn;
        if ((q & 3) == 0 && node < N_NODES) outp[node * 4 + h] = p;
    }
}

// ---------------------------------------------------------------------------
// Kernel A: per-node projections (sj, si, V).
// Grid = 3 x projBlocks — each block does ONE of {Ws->sj, Wv->V, Wd->si}.
// ---------------------------------------------------------------------------
__global__ __launch_bounds__(256) void node_proj_kernel(
    const float* __restrict__ xsrc, const float* __restrict__ xdst,
    const float* __restrict__ Ws, const float* __restrict__ Wd,
    const float* __restrict__ Wv, const float* __restrict__ att,
    float* __restrict__ sj, float* __restrict__ si, float* __restrict__ V,
    int nblk)
{
    __shared__ float xs[128][32];         // 16 KB
    __shared__ float wl[32][HIDD];        // 16 KB
    const int m = blockIdx.x % 3;         // 0:Ws->sj 1:Wv->V 2:Wd->si
    const int b = blockIdx.x / 3;
    const int t = threadIdx.x;
    const int g = t >> 4, q = t & 15;
    const int c0 = q * 8, h = q >> 2;
    const int nb = b * 128;

    const float* x = (m == 2) ? xdst : xsrc;
    const float* W = (m == 0) ? Ws : (m == 1) ? Wv : Wd;

    float acc[8][8];
    #pragma unroll
    for (int a = 0; a < 8; ++a)
        #pragma unroll
        for (int bb = 0; bb < 8; ++bb) acc[a][bb] = 0.f;

    #pragma unroll 1
    for (int kc = 0; kc < 4; ++kc) {
        stage_x32(xs, x, nb, kc, t, N_NODES);
        stage_w32(wl, W, kc, t);
        __syncthreads();
        gemm_chunk(xs, wl, g, c0, acc);
        __syncthreads();
    }

    if (m == 1) {
        #pragma unroll
        for (int nn = 0; nn < 8; ++nn) {
            const int node = nb + g * 8 + nn;
            if (node < N_NODES) {
                *(float4*)&V[(long)node * HIDD + c0] =
                    make_float4(acc[nn][0], acc[nn][1], acc[nn][2], acc[nn][3]);
                *(float4*)&V[(long)node * HIDD + c0 + 4] =
                    make_float4(acc[nn][4], acc[nn][5], acc[nn][6], acc[nn][7]);
            }
        }
    } else if (m == 0) {
        att_reduce_store(acc, att, 0, nb, g, q, h, sj);
    } else {
        att_reduce_store(acc, att, 32, nb, g, q, h, si);
    }
}

// ---------------------------------------------------------------------------
// CSR build (R6): both directions in one pass each.
// ---------------------------------------------------------------------------
__global__ __launch_bounds__(256) void count2_kernel(
    const int* __restrict__ ed0, const int* __restrict__ ed1,
    int* __restrict__ cnt)
{
    const int EB = (NE + 255) / 256;
    const int b = blockIdx.x;
    const int dir = b >= EB;
    const int e = (b - dir * EB) * 256 + threadIdx.x;
    const int* ed = dir ? ed1 : ed0;
    if (e < NE) atomicAdd(&cnt[dir * N_NODES + ed[e]], 1);
}

#define SCAN_T 1024
#define SCAN_CHUNK 49
__global__ __launch_bounds__(1024) void scan2_kernel(
    const int* __restrict__ cnt, int* __restrict__ rowptr)
{
    __shared__ int part[SCAN_T];
    const int dir = blockIdx.x;
    const int* c = cnt + dir * N_NODES;
    int* rp = rowptr + dir * (N_NODES + 8);
    const int t = threadIdx.x;
    const int b = t * SCAN_CHUNK;
    const int e = min(b + SCAN_CHUNK, N_NODES);
    int s = 0;
    for (int i = b; i < e; ++i) s += c[i];
    part[t] = s;
    __syncthreads();
    for (int off = 1; off < SCAN_T; off <<= 1) {
        int v = (t >= off) ? part[t - off] : 0;
        __syncthreads();
        part[t] += v;
        __syncthreads();
    }
    int run = (t > 0) ? part[t - 1] : 0;
    for (int i = b; i < e; ++i) { rp[i] = run; run += c[i]; }
    if (t == SCAN_T - 1) rp[N_NODES] = part[SCAN_T - 1];
}

__global__ __launch_bounds__(256) void scatter2_kernel(
    const int* __restrict__ ed0, const int* __restrict__ ed1,
    const int* __restrict__ rowptr, int* __restrict__ cursor,
    int* __restrict__ eord)
{
    const int EB = (NE + 255) / 256;
    const int b = blockIdx.x;
    const int dir = b >= EB;
    const int e = (b - dir * EB) * 256 + threadIdx.x;
    if (e < NE) {
        const int* ed = dir ? ed1 : ed0;
        const int d = ed[e];
        const int pos = rowptr[dir * (N_NODES + 8) + d]
                      + atomicAdd(&cursor[dir * N_NODES + d], 1);
        eord[dir * NE + pos] = e;
    }
}

// ---------------------------------------------------------------------------
// Kernel B: per-edge logits + exp (no atomics).
// Wt (16 KB) staged once into LDS with the even/odd-quad swizzle.
// Register-tiled GEMM: 128 edges/block, 8 edges x 8 cols per thread, K=32.
// ---------------------------------------------------------------------------
__global__ __launch_bounds__(256, 4) void edge_logits_kernel(
    const int* __restrict__ ei, const float* __restrict__ tfeat,
    const float* __restrict__ Wt, const float* __restrict__ att,
    const float* __restrict__ sj, const float* __restrict__ si,
    float* __restrict__ exbuf)
{
    __shared__ float ts[128][TDIM];       // 16 KB
    __shared__ float wt[TDIM][HIDD];      // 16 KB
    const int t = threadIdx.x;
    const int g = t >> 4, q = t & 15;
    const int c0 = q * 8, h = q >> 2;
    const int wq = c0 >> 1;
    const int eb = blockIdx.x * 128;

    #pragma unroll
    for (int i = 0; i < 4; ++i) {
        int idx = t + i * 256;
        int row = idx >> 3, c4 = idx & 7;
        int col = (c4 ^ ((row >> 3) & 7)) << 2;
        float4 v = make_float4(0.f, 0.f, 0.f, 0.f);
        if (eb + row < NE)
            v = *(const float4*)&tfeat[(long)(eb + row) * TDIM + c4 * 4];
        *(float4*)&ts[row][col] = v;
    }
    stage_w32(wt, Wt, 0, t);
    __syncthreads();

    float acc[8][8];
    #pragma unroll
    for (int a = 0; a < 8; ++a)
        #pragma unroll
        for (int b = 0; b < 8; ++b) acc[a][b] = 0.f;

    #pragma unroll 1
    for (int k4 = 0; k4 < 8; ++k4) {
        float4 xv[8];
        const int col = ((k4 ^ (g & 7)) << 2);
        #pragma unroll
        for (int nn = 0; nn < 8; ++nn)
            xv[nn] = *(const float4*)&ts[g * 8 + nn][col];
        #pragma unroll
        for (int kk = 0; kk < 4; ++kk) {
            const float4 wa = *(const float4*)&wt[k4 * 4 + kk][wq];
            const float4 wb = *(const float4*)&wt[k4 * 4 + kk][64 + wq];
            const float wv[8] = {wa.x, wa.y, wa.z, wa.w, wb.x, wb.y, wb.z, wb.w};
            #pragma unroll
            for (int nn = 0; nn < 8; ++nn) {
                const float xk = (kk == 0) ? xv[nn].x : (kk == 1) ? xv[nn].y
                               : (kk == 2) ? xv[nn].z : xv[nn].w;
                #pragma unroll
                for (int j = 0; j < 8; ++j) acc[nn][j] += xk * wv[j];
            }
        }
    }

    const float* ap = att + h * 96 + 64 + 8 * (q & 3);
    const float4 A0 = *(const float4*)ap, A1 = *(const float4*)(ap + 4);
    const float av[8] = {A0.x, A0.y, A0.z, A0.w, A1.x, A1.y, A1.z, A1.w};
    float st[8];
    #pragma unroll
    for (int nn = 0; nn < 8; ++nn) {
        float p = 0.f;
        #pragma unroll
        for (int j = 0; j < 8; ++j) p += leaky(acc[nn][j]) * av[j];
        p += __shfl_down(p, 2, 4);
        p += __shfl_down(p, 1, 4);
        st[nn] = p;
    }
    if ((q & 3) == 0) {
        #pragma unroll
        for (int nn = 0; nn < 8; ++nn) {
            const int e = eb + g * 8 + nn;
            if (e < NE) {
                const int src = ei[e], dst = ei[NE + e];
                exbuf[e * 4 + h] =
                    __expf(sj[src * 4 + h] + si[dst * 4 + h] + st[nn]);
            }
        }
    }
}

// ---------------------------------------------------------------------------
// Kernel C: CSR gather — one wave per dst, single pass.
// Edge ids loaded VECTORIZED per 64-chunk, broadcast via v_readlane;
// 4 edges per iteration so 12 independent global loads are in flight.
// ---------------------------------------------------------------------------
__global__ __launch_bounds__(256) void gather_kernel(
    const int* __restrict__ rowptr, const int* __restrict__ eord,
    const int* __restrict__ eisrc, const float* __restrict__ tfeat,
    const float* __restrict__ exbuf, const float* __restrict__ Wt,
    const float* __restrict__ V, float* __restrict__ agg)
{
    __shared__ float WtS[TDIM * HIDD];   // 16 KB, natural [k][d]
    __shared__ float uS[4][HIDD];
    const int t = threadIdx.x;
    #pragma unroll
    for (int i = 0; i < 4; ++i)
        *(float4*)&WtS[(t + i * 256) * 4] = *(const float4*)&Wt[(t + i * 256) * 4];
    __syncthreads();

    const int w = t >> 6, l = t & 63;
    const int dst = blockIdx.x * 4 + w;              // exact: 12500*4 = 50000
    const int h = l >> 4, d0 = 2 * l, k0 = d0 & 31;
    const int beg = rowptr[dst], end = rowptr[dst + 1];

    float s = 0.f, a0 = 0.f, a1 = 0.f, u0 = 0.f, u1 = 0.f;

    for (int cb = beg; cb < end; cb += 64) {
        const int m = min(64, end - cb);
        int e_v = 0, s_v = 0;
        if (l < m) {
            e_v = eord[cb + l];                       // coalesced
            s_v = eisrc[e_v];                         // gather, but vector
        }
        int i = 0;
        #pragma unroll 1
        for (; i + 4 <= m; i += 4) {
            const int ea = __builtin_amdgcn_readlane(e_v, i);
            const int eb2 = __builtin_amdgcn_readlane(e_v, i + 1);
            const int ec = __builtin_amdgcn_readlane(e_v, i + 2);
            const int ed = __builtin_amdgcn_readlane(e_v, i + 3);
            const int sa = __builtin_amdgcn_readlane(s_v, i);
            const int sb = __builtin_amdgcn_readlane(s_v, i + 1);
            const int sc = __builtin_amdgcn_readlane(s_v, i + 2);
            const int sd = __builtin_amdgcn_readlane(s_v, i + 3);
            const float  xa = exbuf[ea * 4 + h];
            const float  xb = exbuf[eb2 * 4 + h];
            const float  xc = exbuf[ec * 4 + h];
            const float  xd = exbuf[ed * 4 + h];
            const float2 va = *(const float2*)&V[(long)sa * HIDD + d0];
            const float2 vb = *(const float2*)&V[(long)sb * HIDD + d0];
            const float2 vc = *(const float2*)&V[(long)sc * HIDD + d0];
            const float2 vd = *(const float2*)&V[(long)sd * HIDD + d0];
            const float2 ta = *(const float2*)&tfeat[(long)ea * TDIM + k0];
            const float2 tb = *(const float2*)&tfeat[(long)eb2 * TDIM + k0];
            const float2 tc = *(const float2*)&tfeat[(long)ec * TDIM + k0];
            const float2 td = *(const float2*)&tfeat[(long)ed * TDIM + k0];
            s  += xa;            s  += xb;            s  += xc;            s  += xd;
            a0 += xa * va.x;     a0 += xb * vb.x;     a0 += xc * vc.x;     a0 += xd * vd.x;
            a1 += xa * va.y;     a1 += xb * vb.y;     a1 += xc * vc.y;     a1 += xd * vd.y;
            u0 += xa * ta.x;     u0 += xb * tb.x;     u0 += xc * tc.x;     u0 += xd * td.x;
            u1 += xa * ta.y;     u1 += xb * tb.y;     u1 += xc * tc.y;     u1 += xd * td.y;
        }
        #pragma unroll 1
        for (; i < m; ++i) {
            const int e   = __builtin_amdgcn_readlane(e_v, i);
            const int src = __builtin_amdgcn_readlane(s_v, i);
            const float  ex = exbuf[e * 4 + h];
            const float2 vv = *(const float2*)&V[(long)src * HIDD + d0];
            const float2 tk = *(const float2*)&tfeat[(long)e * TDIM + k0];
            s  += ex;
            a0 += ex * vv.x;  a1 += ex * vv.y;
            u0 += ex * tk.x;  u1 += ex * tk.y;
        }
    }
    *(float2*)&uS[w][d0] = make_float2(u0, u1);      // (h, k0) lives at idx d0
    __syncthreads();

    const float inv = 1.f / (s + 1e-16f);
    float t0 = 0.f, t1 = 0.f;
    #pragma unroll
    for (int k = 0; k < TDIM; ++k) {
        const float uu = uS[w][h * 32 + k];
        const float2 wv = *(const float2*)&WtS[k * HIDD + d0];
        t0 += uu * wv.x;
        t1 += uu * wv.y;
    }
    *(float2*)&agg[(long)dst * HIDD + d0] =
        make_float2((a0 + t0) * inv, (a1 + t1) * inv);
}

// ---------------------------------------------------------------------------
// Kernel D (fused user+item): out = LN(h + agg@Wout + bout)*lnw + lnb
// R11: dual-operand LDS staging with W swizzle, NO prefetch (R10 spill).
// LN via shfl over the 16 threads of each node group.
// ---------------------------------------------------------------------------
__global__ __launch_bounds__(256) void out_kernel(
    const float* __restrict__ agg_u, const float* __restrict__ agg_i,
    const float* __restrict__ h_u,   const float* __restrict__ h_i,
    const float* __restrict__ Wo_u,  const float* __restrict__ Wo_i,
    const float* __restrict__ bo_u,  const float* __restrict__ bo_i,
    const float* __restrict__ lw_u,  const float* __restrict__ lw_i,
    const float* __restrict__ lb_u,  const float* __restrict__ lb_i,
    float* __restrict__ out, int nblk)
{
    __shared__ float ag[128][32];        // 16 KB
    __shared__ float wl[32][HIDD];       // 16 KB
    const int dir = blockIdx.x >= nblk;
    const int b   = blockIdx.x - dir * nblk;
    const float* agg  = dir ? agg_i : agg_u;
    const float* hx   = dir ? h_i   : h_u;
    const float* Wout = dir ? Wo_i  : Wo_u;
    const float* bout = dir ? bo_i  : bo_u;
    const float* lnw  = dir ? lw_i  : lw_u;
    const float* lnb  = dir ? lb_i  : lb_u;
    float* outp = out + (long)dir * N_NODES * HIDD;

    const int t = threadIdx.x;
    const int g = t >> 4, q = t & 15;
    const int c0 = q * 8;
    const int l = t & 63;
    const int nb = b * 128;

    float acc[8][8];
    #pragma unroll
    for (int a = 0; a < 8; ++a)
        #pragma unroll
        for (int bb = 0; bb < 8; ++bb) acc[a][bb] = 0.f;

    #pragma unroll 1
    for (int kc = 0; kc < 4; ++kc) {
        stage_x32(ag, agg, nb, kc, t, N_NODES);
        stage_w32(wl, Wout, kc, t);
        __syncthreads();
        gemm_chunk(ag, wl, g, c0, acc);
        __syncthreads();
    }

    const float4 B0 = *(const float4*)&bout[c0], B1 = *(const float4*)&bout[c0+4];
    const float4 G0 = *(const float4*)&lnw[c0],  G1 = *(const float4*)&lnw[c0+4];
    const float4 L0 = *(const float4*)&lnb[c0],  L1 = *(const float4*)&lnb[c0+4];
    const float bo[8] = {B0.x,B0.y,B0.z,B0.w,B1.x,B1.y,B1.z,B1.w};
    const float gw[8] = {G0.x,G0.y,G0.z,G0.w,G1.x,G1.y,G1.z,G1.w};
    const float gb[8] = {L0.x,L0.y,L0.z,L0.w,L1.x,L1.y,L1.z,L1.w};

    #pragma unroll
    for (int nn = 0; nn < 8; ++nn) {
        const int node = nb + g * 8 + nn;
        const bool valid = node < N_NODES;
        float y[8];
        float4 H0 = make_float4(0,0,0,0), H1 = make_float4(0,0,0,0);
        if (valid) {
            H0 = *(const float4*)&hx[(long)node * HIDD + c0];
            H1 = *(const float4*)&hx[(long)node * HIDD + c0 + 4];
        }
        const float hv[8] = {H0.x,H0.y,H0.z,H0.w,H1.x,H1.y,H1.z,H1.w};
        float s1 = 0.f, s2 = 0.f;
        #pragma unroll
        for (int j = 0; j < 8; ++j) {
            y[j] = hv[j] + acc[nn][j] + bo[j];
            s1 += y[j];
            s2 += y[j] * y[j];
        }
        s1 += __shfl_down(s1, 8, 16); s2 += __shfl_down(s2, 8, 16);
        s1 += __shfl_down(s1, 4, 16); s2 += __shfl_down(s2, 4, 16);
        s1 += __shfl_down(s1, 2, 16); s2 += __shfl_down(s2, 2, 16);
        s1 += __shfl_down(s1, 1, 16); s2 += __shfl_down(s2, 1, 16);
        s1 = __shfl(s1, l & ~15);
        s2 = __shfl(s2, l & ~15);
        const float mu  = s1 * (1.f / 128.f);
        const float var = s2 * (1.f / 128.f) - mu * mu;
        const float inv = rsqrtf(var + 1e-5f);
        if (valid) {
            float o[8];
            #pragma unroll
            for (int j = 0; j < 8; ++j) o[j] = (y[j] - mu) * inv * gw[j] + gb[j];
            *(float4*)&outp[(long)node * HIDD + c0]     = make_float4(o[0],o[1],o[2],o[3]);
            *(float4*)&outp[(long)node * HIDD + c0 + 4] = make_float4(o[4],o[5],o[6],o[7]);
        }
    }
}

// ---------------------------------------------------------------------------
extern "C" void kernel_launch(void* const* d_in, const int* in_sizes, int n_in,
                              void* d_out, int out_size, void* d_ws, size_t ws_size,
                              hipStream_t stream)
{
    const float* h_user    = (const float*)d_in[0];
    const float* h_item    = (const float*)d_in[1];
    const int*   ei_ui     = (const int*)d_in[2];
    const float* t_ui      = (const float*)d_in[3];
    const int*   ei_iu     = (const int*)d_in[4];
    const float* t_iu      = (const float*)d_in[5];
    const float* W_src_ui  = (const float*)d_in[6];
    const float* W_dst_ui  = (const float*)d_in[7];
    const float* W_temp_ui = (const float*)d_in[8];
    const float* W_val_ui  = (const float*)d_in[9];
    const float* att_ui    = (const float*)d_in[10];
    const float* W_src_iu  = (const float*)d_in[11];
    const float* W_dst_iu  = (const float*)d_in[12];
    const float* W_temp_iu = (const float*)d_in[13];
    const float* W_val_iu  = (const float*)d_in[14];
    const float* att_iu    = (const float*)d_in[15];
    const float* Wout_user = (const float*)d_in[16];
    const float* bout_user = (const float*)d_in[17];
    const float* Wout_item = (const float*)d_in[18];
    const float* bout_item = (const float*)d_in[19];
    const float* lnw_user  = (const float*)d_in[20];
    const float* lnb_user  = (const float*)d_in[21];
    const float* lnw_item  = (const float*)d_in[22];
    const float* lnb_item  = (const float*)d_in[23];

    // workspace layout (R6: dual CSR — rowptr/cnt/eord doubled)
    float* agg_item = (float*)d_ws;
    float* agg_user = agg_item + (long)N_NODES * HIDD;
    float* V        = agg_user + (long)N_NODES * HIDD;
    float* sj       = V + (long)N_NODES * HIDD;
    float* si       = sj + (long)N_NODES * 4;
    float* exbuf    = si + (long)N_NODES * 4;
    int*   rowptr   = (int*)(exbuf + (long)NE * 4);   // [2][N_NODES+8]
    int*   cnt      = rowptr + 2 * (N_NODES + 8);     // [2][N_NODES]
    int*   eord     = cnt + 2 * N_NODES;              // [2][NE]

    const int edgeBlocks  = (NE + 255) / 256;         // 1954
    const int logitBlocks = (NE + 127) / 128;         // 3907
    const int dstBlocks   = N_NODES / 4;              // 12500
    const int projBlocks  = (N_NODES + 127) / 128;    // 391

    // --- CSR build for BOTH directions in one pass each ---
    hipMemsetAsync(cnt, 0, 2 * N_NODES * sizeof(int), stream);
    count2_kernel<<<2 * edgeBlocks, 256, 0, stream>>>(ei_ui + NE, ei_iu + NE, cnt);
    scan2_kernel<<<2, SCAN_T, 0, stream>>>(cnt, rowptr);
    hipMemsetAsync(cnt, 0, 2 * N_NODES * sizeof(int), stream);
    scatter2_kernel<<<2 * edgeBlocks, 256, 0, stream>>>(
        ei_ui + NE, ei_iu + NE, rowptr, cnt, eord);

    for (int dir = 0; dir < 2; ++dir) {
        const int*   ei   = dir == 0 ? ei_ui : ei_iu;
        const float* tf   = dir == 0 ? t_ui : t_iu;
        const float* xsrc = dir == 0 ? h_user : h_item;
        const float* xdst = dir == 0 ? h_item : h_user;
        const float* Ws   = dir == 0 ? W_src_ui : W_src_iu;
        const float* Wd   = dir == 0 ? W_dst_ui : W_dst_iu;
        const float* Wt   = dir == 0 ? W_temp_ui : W_temp_iu;
        const float* Wv   = dir == 0 ? W_val_ui : W_val_iu;
        const float* att  = dir == 0 ? att_ui : att_iu;
        float*       agg  = dir == 0 ? agg_item : agg_user;

        node_proj_kernel<<<3 * projBlocks, 256, 0, stream>>>(
            xsrc, xdst, Ws, Wd, Wv, att, sj, si, V, projBlocks);
        edge_logits_kernel<<<logitBlocks, 256, 0, stream>>>(
            ei, tf, Wt, att, sj, si, exbuf);
        gather_kernel<<<dstBlocks, 256, 0, stream>>>(
            rowptr + dir * (N_NODES + 8), eord + dir * NE,
            ei, tf, exbuf, Wt, V, agg);
    }

    out_kernel<<<2 * projBlocks, 256, 0, stream>>>(
        agg_user, agg_item, h_user, h_item,
        Wout_user, Wout_item, bout_user, bout_item,
        lnw_user, lnw_item, lnb_user, lnb_item,
        (float*)d_out, projBlocks);
}